// Round 1
// 430.601 us; speedup vs baseline: 1.7314x; 1.7314x over previous
//
#include <hip/hip_runtime.h>
#include <hip/hip_bf16.h>

typedef unsigned int  uint32;
typedef unsigned short ushort16;

#define B_TOTAL 65536
#define NN 17

typedef __bf16 bf16x8 __attribute__((ext_vector_type(8)));
typedef float  f32x4  __attribute__((ext_vector_type(4)));

// ---- fixed normalized adjacency (from EDGES in the reference) ----
static constexpr int   CNT[NN]    = {2,0,0,0,0,4,4,2,2,1,1,3,3,2,2,1,1};
static constexpr int   NBR[NN][4] = {
  {5,6,0,0},{0,0,0,0},{0,0,0,0},{0,0,0,0},{0,0,0,0},
  {7,6,11,0},{8,5,12,0},{5,9,0,0},{6,10,0,0},{7,0,0,0},{8,0,0,0},
  {5,12,13,0},{6,11,14,0},{11,15,0,0},{12,16,0,0},{13,0,0,0},{14,0,0,0}};
static constexpr float INVDEG[NN] = {0.5f,0.f,0.f,0.f,0.f,0.25f,0.25f,0.5f,0.5f,1.f,1.f,
  0.33333333333333333f,0.33333333333333333f,0.5f,0.5f,1.f,1.f};

// ---- workspace layout (bytes) ----
#define S_BYTES   ((size_t)B_TOTAL * 1088 * 2)
#define STATS_OFF S_BYTES
#define W1_OFF    (STATS_OFF + 1024)
#define W2_OFF    (W1_OFF + (size_t)1088*256*2)
#define WGT_OFF   (W2_OFF + (size_t)65536)   // 4 x 4096 bf16: W1hi, W1lo, W2hi, W2lo

__device__ inline ushort16 f2bfu(float f){
  union { __hip_bfloat16 h; ushort16 u; } c; c.h = __float2bfloat16(f); return c.u;
}

__device__ inline f32x4 MFMA(bf16x8 a, bf16x8 b, f32x4 c){
  return __builtin_amdgcn_mfma_f32_16x16x32_bf16(a, b, c, 0, 0, 0);
}

// encoder + normalized-adjacency aggregate for one batch row, one feature dim e.
__device__ inline void enc_agg(const float* __restrict__ xb,
                               float we0, float we1, float be, float* s1){
  float h[NN];
  #pragma unroll
  for (int n = 0; n < NN; ++n)
    h[n] = fmaxf(fmaf(xb[2*n], we0, fmaf(xb[2*n+1], we1, be)), 0.f);
  #pragma unroll
  for (int n = 0; n < NN; ++n){
    float a = 0.f;
    #pragma unroll
    for (int j = 0; j < 4; ++j) if (j < CNT[n]) a += h[NBR[n][j]];
    s1[n] = fmaf(INVDEG[n], a, h[n]);
  }
}

__device__ inline void reduce_stats(float* sA, float* qA,
                                    float* __restrict__ gSum, float* __restrict__ gSq){
  int t = threadIdx.x;
  #pragma unroll
  for (int n = 0; n < NN; ++n){
    float s = sA[n], q = qA[n];
    #pragma unroll
    for (int off = 32; off > 0; off >>= 1){
      s += __shfl_down(s, off, 64);
      q += __shfl_down(q, off, 64);
    }
    sA[n] = s; qA[n] = q;
  }
  __shared__ float shS[NN], shQ[NN];
  if (t < NN){ shS[t] = 0.f; shQ[t] = 0.f; }
  __syncthreads();
  if ((t & 63) == 0){
    #pragma unroll
    for (int n = 0; n < NN; ++n){ atomicAdd(&shS[n], sA[n]); atomicAdd(&shQ[n], qA[n]); }
  }
  __syncthreads();
  if (t < NN){ atomicAdd(&gSum[t], shS[t]); atomicAdd(&gSq[t], shQ[t]); }
}

// ---- pre-cast + TRANSPOSE weights to bf16 fragment-friendly layouts ----
// W1T[n][k] = W_p1[k][n]; W2T[e][k] = W_p2[k][e];
// WGT: [0:4096) Wg1T_hi[e][d], [4096:8192) Wg1T_lo, [8192..) Wg2T_hi, Wg2T_lo
__global__ __launch_bounds__(256) void k_prep(const float* __restrict__ Wp1,
                                              const float* __restrict__ Wp2,
                                              const float* __restrict__ Wg1,
                                              const float* __restrict__ Wg2,
                                              ushort16* __restrict__ W1T,
                                              ushort16* __restrict__ W2T,
                                              ushort16* __restrict__ WGT){
  int g = blockIdx.x * 256 + threadIdx.x;          // 1280*256 = 327,680
  if (g < 278528){
    int n = g / 1088, k = g - n*1088;              // W1T[n][k] = W_p1[k][n]
    W1T[g] = f2bfu(Wp1[(size_t)k*256 + n]);
  } else if (g < 311296){
    int h = g - 278528;
    int e = h >> 8, k = h & 255;                   // W2T[e][k] = W_p2[k][e]
    W2T[h] = f2bfu(Wp2[(size_t)k*128 + e]);
  } else if (g < 327680){
    int h = g - 311296;                            // 0..16383
    int sel = h >> 12;                             // 0:W1hi 1:W1lo 2:W2hi 3:W2lo
    int idx = h & 4095;
    int e = idx >> 6, d = idx & 63;
    const float* Wsrc = (sel < 2) ? Wg1 : Wg2;
    float v = Wsrc[d*64 + e];                      // WT[e][d] = W[d][e]
    __hip_bfloat16 hi = __float2bfloat16(v);
    if (sel & 1){
      float rem = v - __bfloat162float(hi);
      WGT[h] = f2bfu(rem);
    } else {
      WGT[h] = f2bfu(v);
    }
  }
}

// ---- pass 1: BN1 statistics over s1 = enc+agg ----
__global__ __launch_bounds__(256,2) void k_stats1(const float* __restrict__ x,
    const float* __restrict__ W_enc, const float* __restrict__ b_enc,
    float* __restrict__ gSum, float* __restrict__ gSq){
  int t = threadIdx.x, e = t & 63, lb = t >> 6;
  float we0 = W_enc[e], we1 = W_enc[64 + e], be = b_enc[e];
  float sA[NN], qA[NN];
  #pragma unroll
  for (int n = 0; n < NN; ++n){ sA[n] = 0.f; qA[n] = 0.f; }
  size_t b0 = (size_t)blockIdx.x * 32;
  for (int it = 0; it < 8; ++it){
    size_t b = b0 + it*4 + lb;
    float s1[NN];
    enc_agg(x + b*34, we0, we1, be, s1);
    #pragma unroll
    for (int n = 0; n < NN; ++n){ sA[n] += s1[n]; qA[n] += s1[n]*s1[n]; }
  }
  reduce_stats(sA, qA, gSum, gSq);
}

__global__ void k_finalize(const float* __restrict__ gSum, const float* __restrict__ gSq,
                           const float* __restrict__ gamma, const float* __restrict__ beta,
                           float* __restrict__ scale, float* __restrict__ shift){
  int n = threadIdx.x;
  if (n < NN){
    const float invC = 1.0f / (float)((size_t)B_TOTAL * 64);
    float mean = gSum[n] * invC;
    float var  = gSq[n]  * invC - mean*mean;
    float istd = rsqrtf(var + 1e-5f);
    float sc   = gamma[n] * istd;
    scale[n] = sc;
    shift[n] = fmaf(-mean, sc, beta[n]);
  }
}

// ---- pass 2: enc+agg, BN1 -> hn(bf16 LDS), MFMA gc1, relu, agg -> S + BN2 stats ----
// 16 batch rows / block -> 272 (b,n) rows = 17 M-tiles of 16. 4 waves.
// LDS hn/h2: [272][64] bf16, row stride 128B, XOR-swizzled by ((row&7)<<4).
__global__ __launch_bounds__(256,2) void k_gc1(const float* __restrict__ x,
    const float* __restrict__ W_enc, const float* __restrict__ b_enc,
    const float* __restrict__ bg,
    const float* __restrict__ scale, const float* __restrict__ shift,
    const __hip_bfloat16* __restrict__ Whi, const __hip_bfloat16* __restrict__ Wlo,
    __hip_bfloat16* __restrict__ S, float* __restrict__ gSum, float* __restrict__ gSq){
  __shared__ __align__(16) char hsm[272*128];
  __shared__ float sc_s[NN], sf_s[NN];
  const int t = threadIdx.x, e = t & 63, lb = t >> 6;
  const int w4 = t >> 6, lo = t & 15, q = (t >> 4) & 3;
  const size_t b0 = (size_t)blockIdx.x * 16;
  if (t < NN){ sc_s[t] = scale[t]; sf_s[t] = shift[t]; }
  float we0 = W_enc[e], we1 = W_enc[64 + e], be = b_enc[e];
  __syncthreads();

  // phase 1: enc + agg + BN1-apply -> hn bf16 LDS
  for (int it = 0; it < 4; ++it){
    int bl = it*4 + lb;
    size_t b = b0 + bl;
    float s1[NN];
    enc_agg(x + b*34, we0, we1, be, s1);
    #pragma unroll
    for (int n = 0; n < NN; ++n){
      int row = bl*17 + n;
      int byte = (row*128 + 2*e) ^ ((row & 7) << 4);
      *(__hip_bfloat16*)(hsm + byte) = __float2bfloat16(fmaf(s1[n], sc_s[n], sf_s[n]));
    }
  }
  __syncthreads();

  // phase 2: h2 = hn @ (Whi + Wlo), D rows=(b,n), cols=e
  const char* WhiB = (const char*)Whi;
  const char* WloB = (const char*)Wlo;
  f32x4 acc[5][4];
  #pragma unroll
  for (int i = 0; i < 5; ++i)
    #pragma unroll
    for (int et = 0; et < 4; ++et) acc[i][et] = (f32x4)0.f;
  #pragma unroll
  for (int et = 0; et < 4; ++et){
    int col = et*16 + lo;
    bf16x8 wh0 = *(const bf16x8*)(WhiB + col*128 +      q*16);
    bf16x8 wh1 = *(const bf16x8*)(WhiB + col*128 + 64 + q*16);
    bf16x8 wl0 = *(const bf16x8*)(WloB + col*128 +      q*16);
    bf16x8 wl1 = *(const bf16x8*)(WloB + col*128 + 64 + q*16);
    #pragma unroll
    for (int i = 0; i < 5; ++i){
      int mt = w4 + i*4;
      if (mt < 17){
        int r = mt*16 + lo;
        int base = r*128, sw = (r & 7) << 4;
        bf16x8 a0 = *(const bf16x8*)(hsm + ((base +      q*16) ^ sw));
        bf16x8 a1 = *(const bf16x8*)(hsm + ((base + 64 + q*16) ^ sw));
        acc[i][et] = MFMA(a0, wh0, acc[i][et]);
        acc[i][et] = MFMA(a1, wh1, acc[i][et]);
        acc[i][et] = MFMA(a0, wl0, acc[i][et]);
        acc[i][et] = MFMA(a1, wl1, acc[i][et]);
      }
    }
  }
  float bgv[4];
  #pragma unroll
  for (int et = 0; et < 4; ++et) bgv[et] = bg[et*16 + lo];
  __syncthreads();

  // writeback: h2 = relu(acc + bias) -> reuse hsm (same swizzled layout)
  #pragma unroll
  for (int i = 0; i < 5; ++i){
    int mt = w4 + i*4;
    if (mt < 17){
      #pragma unroll
      for (int et = 0; et < 4; ++et){
        #pragma unroll
        for (int j = 0; j < 4; ++j){
          int row = mt*16 + q*4 + j;
          float h2 = fmaxf(acc[i][et][j] + bgv[et], 0.f);
          int byte = (row*128 + (et*16 + lo)*2) ^ ((row & 7) << 4);
          *(__hip_bfloat16*)(hsm + byte) = __float2bfloat16(h2);
        }
      }
    }
  }
  __syncthreads();

  // phase 3: aggregate, store S (bf16), BN2 stats
  float sA[NN], qA[NN];
  #pragma unroll
  for (int n = 0; n < NN; ++n){ sA[n] = 0.f; qA[n] = 0.f; }
  for (int it = 0; it < 4; ++it){
    int bl = it*4 + lb;
    size_t b = b0 + bl;
    int row0 = bl*17;
    float h2v[NN];
    #pragma unroll
    for (int n = 0; n < NN; ++n){
      int row = row0 + n;
      int byte = (row*128 + 2*e) ^ ((row & 7) << 4);
      h2v[n] = __bfloat162float(*(const __hip_bfloat16*)(hsm + byte));
    }
    #pragma unroll
    for (int n = 0; n < NN; ++n){
      float agg = 0.f;
      #pragma unroll
      for (int j = 0; j < 4; ++j) if (j < CNT[n]) agg += h2v[NBR[n][j]];
      float s2 = fmaf(INVDEG[n], agg, h2v[n]);
      __hip_bfloat16 hb = __float2bfloat16(s2);
      S[b*1088 + n*64 + e] = hb;
      float sr = __bfloat162float(hb);
      sA[n] += sr; qA[n] += sr*sr;
    }
  }
  reduce_stats(sA, qA, gSum, gSq);
}

// ---- pass 3a: BN2 -> hn(bf16 LDS), MFMA gc2, relu -> S in place (no agg after gc2) ----
__global__ __launch_bounds__(256,2) void k_gc2(
    const float* __restrict__ bg,
    const float* __restrict__ scale, const float* __restrict__ shift,
    const __hip_bfloat16* __restrict__ Whi, const __hip_bfloat16* __restrict__ Wlo,
    __hip_bfloat16* S){
  __shared__ __align__(16) char hsm[272*128];
  __shared__ float sc_s[NN], sf_s[NN];
  const int t = threadIdx.x, e = t & 63, lb = t >> 6;
  const int w4 = t >> 6, lo = t & 15, q = (t >> 4) & 3;
  const size_t b0 = (size_t)blockIdx.x * 16;
  if (t < NN){ sc_s[t] = scale[t]; sf_s[t] = shift[t]; }
  __syncthreads();

  // phase 1: read S, BN2-apply -> hn bf16 LDS
  for (int it = 0; it < 4; ++it){
    int bl = it*4 + lb;
    size_t b = b0 + bl;
    #pragma unroll
    for (int n = 0; n < NN; ++n){
      float v = __bfloat162float(S[b*1088 + n*64 + e]);
      int row = bl*17 + n;
      int byte = (row*128 + 2*e) ^ ((row & 7) << 4);
      *(__hip_bfloat16*)(hsm + byte) = __float2bfloat16(fmaf(v, sc_s[n], sf_s[n]));
    }
  }
  __syncthreads();

  // phase 2: h3 = relu(hn @ (Whi+Wlo) + bg) -> store straight to S
  const char* WhiB = (const char*)Whi;
  const char* WloB = (const char*)Wlo;
  f32x4 acc[5][4];
  #pragma unroll
  for (int i = 0; i < 5; ++i)
    #pragma unroll
    for (int et = 0; et < 4; ++et) acc[i][et] = (f32x4)0.f;
  #pragma unroll
  for (int et = 0; et < 4; ++et){
    int col = et*16 + lo;
    bf16x8 wh0 = *(const bf16x8*)(WhiB + col*128 +      q*16);
    bf16x8 wh1 = *(const bf16x8*)(WhiB + col*128 + 64 + q*16);
    bf16x8 wl0 = *(const bf16x8*)(WloB + col*128 +      q*16);
    bf16x8 wl1 = *(const bf16x8*)(WloB + col*128 + 64 + q*16);
    #pragma unroll
    for (int i = 0; i < 5; ++i){
      int mt = w4 + i*4;
      if (mt < 17){
        int r = mt*16 + lo;
        int base = r*128, sw = (r & 7) << 4;
        bf16x8 a0 = *(const bf16x8*)(hsm + ((base +      q*16) ^ sw));
        bf16x8 a1 = *(const bf16x8*)(hsm + ((base + 64 + q*16) ^ sw));
        acc[i][et] = MFMA(a0, wh0, acc[i][et]);
        acc[i][et] = MFMA(a1, wh1, acc[i][et]);
        acc[i][et] = MFMA(a0, wl0, acc[i][et]);
        acc[i][et] = MFMA(a1, wl1, acc[i][et]);
      }
    }
  }
  float bgv[4];
  #pragma unroll
  for (int et = 0; et < 4; ++et) bgv[et] = bg[et*16 + lo];

  const size_t g0 = b0 * 17;   // flat (b*17+n) row base; S layout is [row][64]
  #pragma unroll
  for (int i = 0; i < 5; ++i){
    int mt = w4 + i*4;
    if (mt < 17){
      #pragma unroll
      for (int et = 0; et < 4; ++et){
        #pragma unroll
        for (int j = 0; j < 4; ++j){
          int row = mt*16 + q*4 + j;
          float h3 = fmaxf(acc[i][et][j] + bgv[et], 0.f);
          S[(g0 + row)*64 + et*16 + lo] = __float2bfloat16(h3);
        }
      }
    }
  }
}

// ---- pass 3b: MFMA pooled MLP + L2 normalize (unchanged) ----
__global__ __launch_bounds__(256,2) void k_mlp(const ushort16* __restrict__ S,
    const ushort16* __restrict__ W1T, const float* __restrict__ b_p1,
    const ushort16* __restrict__ W2T, const float* __restrict__ b_p2,
    float* __restrict__ out){
  __shared__ __align__(16) char smem[65536];
  const int t = threadIdx.x;
  const int L = t & 63, w = t >> 6;
  const int lo = L & 15, q = L >> 4;
  const size_t b0 = (size_t)blockIdx.x * 128;
  const char* Sb  = (const char*)S;
  const char* W1b = (const char*)W1T;
  const char* W2b = (const char*)W2T;

  f32x4 acc[16][2];
  #pragma unroll
  for (int nt = 0; nt < 16; ++nt){ acc[nt][0] = (f32x4)0.f; acc[nt][1] = (f32x4)0.f; }

  uint4 pr0, pr1, wr0, wr1, wr2, wr3;
  const int rowP = t >> 2,            partP = t & 3;      // P: idx = i*256+t
  const int rowP2 = (256 + t) >> 2,   partP2 = t & 3;
  auto loadG = [&](int ks){
    size_t kb = (size_t)ks * 64;
    pr0 = *(const uint4*)(Sb + (b0 + rowP )*2176 + kb + partP *16);
    pr1 = *(const uint4*)(Sb + (b0 + rowP2)*2176 + kb + partP2*16);
    wr0 = *(const uint4*)(W1b + (size_t)((  0 + t) >> 2)*2176 + kb + partP*16);
    wr1 = *(const uint4*)(W1b + (size_t)((256 + t) >> 2)*2176 + kb + partP*16);
    wr2 = *(const uint4*)(W1b + (size_t)((512 + t) >> 2)*2176 + kb + partP*16);
    wr3 = *(const uint4*)(W1b + (size_t)((768 + t) >> 2)*2176 + kb + partP*16);
  };
  auto writeL = [&](int buf){
    char* Pb = smem + (buf ? 8192 : 0);
    char* Wb = smem + 16384 + (buf ? 16384 : 0);
    *(uint4*)(Pb + (size_t)t*16)          = pr0;
    *(uint4*)(Pb + (size_t)(256 + t)*16)  = pr1;
    *(uint4*)(Wb + (size_t)t*16)          = wr0;
    *(uint4*)(Wb + (size_t)(256 + t)*16)  = wr1;
    *(uint4*)(Wb + (size_t)(512 + t)*16)  = wr2;
    *(uint4*)(Wb + (size_t)(768 + t)*16)  = wr3;
  };

  loadG(0); writeL(0);
  __syncthreads();
  #pragma unroll 1
  for (int ks = 0; ks < 34; ++ks){
    const int cur = ks & 1;
    const char* Pb = smem + (cur ? 8192 : 0);
    const char* Wb = smem + 16384 + (cur ? 16384 : 0);
    if (ks < 33) loadG(ks + 1);
    bf16x8 pf0 = *(const bf16x8*)(Pb + (w*32 +  0 + lo)*64 + q*16);
    bf16x8 pf1 = *(const bf16x8*)(Pb + (w*32 + 16 + lo)*64 + q*16);
    #pragma unroll
    for (int nt = 0; nt < 16; ++nt){
      bf16x8 wf = *(const bf16x8*)(Wb + (nt*16 + lo)*64 + q*16);
      acc[nt][0] = MFMA(wf, pf0, acc[nt][0]);
      acc[nt][1] = MFMA(wf, pf1, acc[nt][1]);
    }
    if (ks < 33) writeL(cur ^ 1);
    __syncthreads();
  }

  // epilogue 1: z = relu(z^T + b_p1) -> LDS bf16 [b][256], 8B-granule XOR swizzle by (b&7)
  #pragma unroll
  for (int nt = 0; nt < 16; ++nt){
    float4 bias = *(const float4*)&b_p1[nt*16 + q*4];
    #pragma unroll
    for (int bt = 0; bt < 2; ++bt){
      int b = w*32 + bt*16 + lo;
      f32x4 v = acc[nt][bt];
      float z0 = fmaxf(v.x + bias.x, 0.f), z1 = fmaxf(v.y + bias.y, 0.f);
      float z2 = fmaxf(v.z + bias.z, 0.f), z3 = fmaxf(v.w + bias.w, 0.f);
      uint32 lo32 = (uint32)f2bfu(z0) | ((uint32)f2bfu(z1) << 16);
      uint32 hi32 = (uint32)f2bfu(z2) | ((uint32)f2bfu(z3) << 16);
      int nbyte = (nt*16 + q*4) * 2;
      int addr = b*512 + (nbyte ^ ((b & 7) << 4));
      *(uint2*)(smem + addr) = make_uint2(lo32, hi32);
    }
  }
  __syncthreads();

  // phase 2: emb^T = W2T @ z^T  (K=256, 8 k-steps)
  f32x4 acc2[8][2];
  #pragma unroll
  for (int et = 0; et < 8; ++et){ acc2[et][0] = (f32x4)0.f; acc2[et][1] = (f32x4)0.f; }
  #pragma unroll 1
  for (int ks = 0; ks < 8; ++ks){
    bf16x8 zf0, zf1;
    {
      int b = w*32 + lo;
      int kb = ks*64 + q*16;
      zf0 = *(const bf16x8*)(smem + b*512 + (kb ^ ((b & 7) << 4)));
      b = w*32 + 16 + lo;
      zf1 = *(const bf16x8*)(smem + b*512 + (kb ^ ((b & 7) << 4)));
    }
    #pragma unroll
    for (int et = 0; et < 8; ++et){
      bf16x8 wf = *(const bf16x8*)(W2b + (et*16 + lo)*512 + ks*64 + q*16);
      acc2[et][0] = MFMA(wf, zf0, acc2[et][0]);
      acc2[et][1] = MFMA(wf, zf1, acc2[et][1]);
    }
  }

  // epilogue 2: + b_p2, L2-normalize rows (b), float4 stores
  #pragma unroll
  for (int bt = 0; bt < 2; ++bt){
    int b = w*32 + bt*16 + lo;
    float4 vv[8];
    float ss = 0.f;
    #pragma unroll
    for (int et = 0; et < 8; ++et){
      float4 bias = *(const float4*)&b_p2[et*16 + q*4];
      f32x4 a = bt ? acc2[et][1] : acc2[et][0];
      vv[et].x = a.x + bias.x; vv[et].y = a.y + bias.y;
      vv[et].z = a.z + bias.z; vv[et].w = a.w + bias.w;
      ss += vv[et].x*vv[et].x + vv[et].y*vv[et].y + vv[et].z*vv[et].z + vv[et].w*vv[et].w;
    }
    ss += __shfl_xor(ss, 16, 64);
    ss += __shfl_xor(ss, 32, 64);
    float inv = 1.0f / fmaxf(sqrtf(ss), 1e-12f);
    float* op = out + (b0 + b)*128;
    #pragma unroll
    for (int et = 0; et < 8; ++et){
      float4 o; o.x = vv[et].x*inv; o.y = vv[et].y*inv; o.z = vv[et].z*inv; o.w = vv[et].w*inv;
      *(float4*)(op + et*16 + q*4) = o;
    }
  }
}

extern "C" void kernel_launch(void* const* d_in, const int* in_sizes, int n_in,
                              void* d_out, int out_size, void* d_ws, size_t ws_size,
                              hipStream_t stream) {
  const float* x     = (const float*)d_in[0];
  const float* W_enc = (const float*)d_in[1];
  const float* b_enc = (const float*)d_in[2];
  const float* W_gc1 = (const float*)d_in[3];
  const float* b_gc1 = (const float*)d_in[4];
  const float* W_gc2 = (const float*)d_in[5];
  const float* b_gc2 = (const float*)d_in[6];
  const float* gamma1= (const float*)d_in[7];
  const float* beta1 = (const float*)d_in[8];
  const float* gamma2= (const float*)d_in[9];
  const float* beta2 = (const float*)d_in[10];
  const float* W_p1  = (const float*)d_in[11];
  const float* b_p1  = (const float*)d_in[12];
  const float* W_p2  = (const float*)d_in[13];
  const float* b_p2  = (const float*)d_in[14];
  float* out = (float*)d_out;

  char* ws = (char*)d_ws;
  __hip_bfloat16* S = (__hip_bfloat16*)ws;
  float*    stats = (float*)(ws + STATS_OFF);
  ushort16* W1T   = (ushort16*)(ws + W1_OFF);
  ushort16* W2T   = (ushort16*)(ws + W2_OFF);
  __hip_bfloat16* WGT = (__hip_bfloat16*)(ws + WGT_OFF);

  (void)hipMemsetAsync(stats, 0, 512, stream);

  k_prep<<<1280, 256, 0, stream>>>(W_p1, W_p2, W_gc1, W_gc2, W1T, W2T, (ushort16*)WGT);
  k_stats1<<<2048, 256, 0, stream>>>(x, W_enc, b_enc, stats + 0, stats + 32);
  k_finalize<<<1, 32, 0, stream>>>(stats + 0, stats + 32, gamma1, beta1, stats + 128, stats + 160);
  k_gc1<<<4096, 256, 0, stream>>>(x, W_enc, b_enc, b_gc1,
                                  stats + 128, stats + 160,
                                  WGT, WGT + 4096,
                                  S, stats + 64, stats + 96);
  k_finalize<<<1, 32, 0, stream>>>(stats + 64, stats + 96, gamma2, beta2, stats + 192, stats + 224);
  k_gc2<<<4096, 256, 0, stream>>>(b_gc2, stats + 192, stats + 224,
                                  WGT + 8192, WGT + 12288, S);
  k_mlp<<<512, 256, 0, stream>>>((const ushort16*)S, W1T, b_p1, (const ushort16*)W2T, b_p2, out);
}